// Round 2
// baseline (464.288 us; speedup 1.0000x reference)
//
#include <hip/hip_runtime.h>

#define NFREQ   257
#define NFRAMES 3751
#define NS      480000
#define HOP     128
#define WIN     512

#define BM 64      // freq tile
#define BN 256     // frame tile (64 per wave)
#define BK 64      // K stage

#define NB      32
#define XP_REAL 480512              // reflect-padded valid length
#define XPS     491904              // per-batch stride incl. zero slack to frame 3839
#define AROWS   320                 // freq rows padded to 5*64

typedef __attribute__((ext_vector_type(8))) short short8;
typedef __attribute__((ext_vector_type(4))) float f32x4;

__device__ __forceinline__ short f2bf(float f) {
    __bf16 b = (__bf16)f;
    return __builtin_bit_cast(short, b);
}

__device__ __forceinline__ void gload_lds16(const void* g, void* l) {
    __builtin_amdgcn_global_load_lds(
        (const __attribute__((address_space(1))) void*)g,
        (__attribute__((address_space(3))) void*)l,
        16, 0, 0);
}

// swizzled byte offset inside a [rows][64] bf16 tile (row stride 128B)
__device__ __forceinline__ int swz(int row, int colByte) {
    return row * 128 + (colByte ^ ((row & 7) << 4));
}

// ---- prep 1: reflect-pad + bf16-convert x into ws ----
__global__ __launch_bounds__(256)
void prep_x(const float* __restrict__ x, short* __restrict__ xp) {
    int g = blockIdx.x * 256 + threadIdx.x;          // one 8-elem group
    int b = g / 61488;                               // XPS/8 groups per batch
    if (b >= NB) return;
    int i8 = (g - b * 61488) * 8;
    const float* __restrict__ xb = x + (size_t)b * NS;
    short8 v;
    int ix = i8 - 256;
    if (ix >= 0 && ix + 8 <= NS && i8 + 8 <= XP_REAL) {
        const float4* p = reinterpret_cast<const float4*>(xb + ix);
        float4 a0 = p[0], a1 = p[1];
        v[0]=f2bf(a0.x); v[1]=f2bf(a0.y); v[2]=f2bf(a0.z); v[3]=f2bf(a0.w);
        v[4]=f2bf(a1.x); v[5]=f2bf(a1.y); v[6]=f2bf(a1.z); v[7]=f2bf(a1.w);
    } else if (i8 >= XP_REAL) {
        #pragma unroll
        for (int j = 0; j < 8; ++j) v[j] = 0;        // zero slack (frames > 3750)
    } else {
        #pragma unroll
        for (int j = 0; j < 8; ++j) {
            int idx = ix + j;
            idx = idx < 0 ? -idx : idx;
            idx = idx >= NS ? 2 * NS - 2 - idx : idx;
            v[j] = f2bf(xb[idx]);
        }
    }
    *reinterpret_cast<short8*>(xp + (size_t)b * XPS + i8) = v;
}

// ---- prep 2: bf16 basis, rows padded to 320 ----
__global__ __launch_bounds__(256)
void prep_basis(const float* __restrict__ basis, short* __restrict__ ab) {
    int g = blockIdx.x * 256 + threadIdx.x;          // 2*320*512/8 = 40960 groups
    if (g >= 40960) return;
    int ri  = g / 20480;
    int rem = g - ri * 20480;
    int r   = rem >> 6;
    int k   = (rem & 63) * 8;
    short8 v;
    if (r < NFREQ) {
        const float4* p = reinterpret_cast<const float4*>(basis + ((size_t)(ri * NFREQ + r)) * WIN + k);
        float4 a0 = p[0], a1 = p[1];
        v[0]=f2bf(a0.x); v[1]=f2bf(a0.y); v[2]=f2bf(a0.z); v[3]=f2bf(a0.w);
        v[4]=f2bf(a1.x); v[5]=f2bf(a1.y); v[6]=f2bf(a1.z); v[7]=f2bf(a1.w);
    } else {
        #pragma unroll
        for (int j = 0; j < 8; ++j) v[j] = 0;
    }
    *reinterpret_cast<short8*>(ab + ((size_t)ri * AROWS + r) * WIN + k) = v;
}

// ---- main GEMM ----
__global__ __launch_bounds__(256, 3)
void stft_mfma_kernel(const short* __restrict__ xp,
                      const short* __restrict__ ab,
                      float* __restrict__ out)
{
    __shared__ __align__(16) char smem[49152];
    char* const ar = smem;           //  8 KB chunks 0-7
    char* const ai = smem + 8192;    //  8 KB chunks 8-15
    char* const xs = smem + 16384;   // 32 KB chunks 16-47

    const int tid  = threadIdx.x;
    const int wave = tid >> 6;
    const int lane = tid & 63;

    // bijective XCD-chunk swizzle (2400 = 8 * 300), freq tile fastest
    int logical = (blockIdx.x & 7) * 300 + (blockIdx.x >> 3);
    int fq   = logical % 5;
    int rest = logical / 5;
    int ft   = rest % 15;
    int b    = rest / 15;
    const int f0 = fq * BM;
    const int t0 = ft * BN;

    const short* __restrict__ xpb = xp + (size_t)b * XPS;
    const short* __restrict__ arG = ab;
    const short* __restrict__ aiG = ab + (size_t)AROWS * WIN;

    f32x4 accR[4][4], accI[4][4];
    #pragma unroll
    for (int i = 0; i < 4; ++i)
        #pragma unroll
        for (int j = 0; j < 4; ++j) {
            accR[i][j] = f32x4{0.f, 0.f, 0.f, 0.f};
            accI[i][j] = f32x4{0.f, 0.f, 0.f, 0.f};
        }

    for (int ks = 0; ks < WIN; ks += BK) {
        __syncthreads();                      // readers of previous stage done

        // stage 48 KB = 48 wave-chunks of 1024B; 12 per wave.
        // linear LDS dest (wave-uniform base), pre-swizzled global source.
        #pragma unroll
        for (int i = 0; i < 12; ++i) {
            int c  = wave * 12 + i;
            int cc = c < 8 ? c : (c < 16 ? c - 8 : c - 16);
            int q   = cc * 64 + lane;
            int row = q >> 3;
            int cbs = ((q & 7) * 16) ^ ((row & 7) << 4);
            const char* src;
            if (c < 8)
                src = (const char*)(arG + (size_t)(f0 + row) * WIN + ks) + cbs;
            else if (c < 16)
                src = (const char*)(aiG + (size_t)(f0 + row) * WIN + ks) + cbs;
            else
                src = (const char*)(xpb + (size_t)(t0 + row) * HOP + ks) + cbs;
            gload_lds16(src, smem + c * 1024);
        }
        asm volatile("s_waitcnt vmcnt(0)" ::: "memory");
        __syncthreads();

        #pragma unroll
        for (int ko = 0; ko < 2; ++ko) {
            const int kb = ko * 64 + (lane >> 4) * 16;  // byte col of this lane's 8 bf16
            short8 xv[4];
            #pragma unroll
            for (int nt = 0; nt < 4; ++nt) {
                int row = wave * 64 + nt * 16 + (lane & 15);
                xv[nt] = *reinterpret_cast<const short8*>(xs + swz(row, kb));
            }
            #pragma unroll
            for (int mf = 0; mf < 4; ++mf) {
                int row = mf * 16 + (lane & 15);
                short8 aRv = *reinterpret_cast<const short8*>(ar + swz(row, kb));
                short8 aIv = *reinterpret_cast<const short8*>(ai + swz(row, kb));
                #pragma unroll
                for (int nt = 0; nt < 4; ++nt) {
                    accR[mf][nt] = __builtin_amdgcn_mfma_f32_16x16x32_bf16(aRv, xv[nt], accR[mf][nt], 0, 0, 0);
                    accI[mf][nt] = __builtin_amdgcn_mfma_f32_16x16x32_bf16(aIv, xv[nt], accI[mf][nt], 0, 0, 0);
                }
            }
        }
    }

    // epilogue: magnitude + masked store
    // C/D layout: col = lane&15 (frame), row = (lane>>4)*4 + reg (freq)
    const int tBase = t0 + wave * 64 + (lane & 15);
    const int fBase = f0 + (lane >> 4) * 4;
    #pragma unroll
    for (int mf = 0; mf < 4; ++mf) {
        #pragma unroll
        for (int nt = 0; nt < 4; ++nt) {
            int t = tBase + nt * 16;
            if (t >= NFRAMES) continue;
            #pragma unroll
            for (int r = 0; r < 4; ++r) {
                int f = fBase + mf * 16 + r;
                if (f < NFREQ) {
                    float vr = accR[mf][nt][r], vi = accI[mf][nt][r];
                    out[((size_t)b * NFREQ + f) * NFRAMES + t] = sqrtf(vr * vr + vi * vi);
                }
            }
        }
    }
}

extern "C" void kernel_launch(void* const* d_in, const int* in_sizes, int n_in,
                              void* d_out, int out_size, void* d_ws, size_t ws_size,
                              hipStream_t stream) {
    const float* x     = (const float*)d_in[0];
    const float* basis = (const float*)d_in[1];
    float* out = (float*)d_out;

    short* xp = (short*)d_ws;                         // 32*491904 bf16
    short* ab = xp + (size_t)NB * XPS;                // 2*320*512 bf16

    prep_x<<<dim3((NB * (XPS / 8) + 255) / 256), 256, 0, stream>>>(x, xp);
    prep_basis<<<dim3(160), 256, 0, stream>>>(basis, ab);

    dim3 grid(8 * 300);                               // 5 freq * 15 frame * 32 batch
    stft_mfma_kernel<<<grid, 256, 0, stream>>>(xp, ab, out);
}

// Round 5
// 118.167 us; speedup vs baseline: 3.9291x; 3.9291x over previous
//
#include <hip/hip_runtime.h>

#define NFREQ   257
#define NFRAMES 3751
#define NS      480000
#define HOP     128
#define WIN     512

#define NB      32
#define XP_REAL 480512              // reflect-padded valid length
#define XPS     491904              // per-batch stride incl. zero slack to frame 3839
#define AROWS   320                 // freq rows padded to 5*64
#define AIMAG_B 327680              // byte offset of imag basis plane (320*512*2)

#define BN      128                 // frames per block
#define NFT     30                  // frame tiles (30*128 = 3840)
#define STEPS   40                  // 5 fq * 8 ks
#define XW_B    33792               // x-window LDS alloc (33536 used)
#define AHALF   16384               // one A buffer: ar 8KB + ai 8KB

typedef __attribute__((ext_vector_type(8))) short short8;
typedef __attribute__((ext_vector_type(4))) float f32x4;

__device__ __forceinline__ short f2bf(float f) {
    __bf16 b = (__bf16)f;
    return __builtin_bit_cast(short, b);
}

__device__ __forceinline__ void gload_lds16(const void* g, void* l) {
    __builtin_amdgcn_global_load_lds(
        (const __attribute__((address_space(1))) void*)g,
        (__attribute__((address_space(3))) void*)l,
        16, 0, 0);
}

// ---- prep 1: reflect-pad + bf16-convert x into ws ----
__global__ __launch_bounds__(256)
void prep_x(const float* __restrict__ x, short* __restrict__ xp) {
    int g = blockIdx.x * 256 + threadIdx.x;          // one 8-elem group
    int b = g / 61488;                               // XPS/8 groups per batch
    if (b >= NB) return;
    int i8 = (g - b * 61488) * 8;
    const float* __restrict__ xb = x + (size_t)b * NS;
    short8 v;
    int ix = i8 - 256;
    if (ix >= 0 && ix + 8 <= NS && i8 + 8 <= XP_REAL) {
        const float4* p = reinterpret_cast<const float4*>(xb + ix);
        float4 a0 = p[0], a1 = p[1];
        v[0]=f2bf(a0.x); v[1]=f2bf(a0.y); v[2]=f2bf(a0.z); v[3]=f2bf(a0.w);
        v[4]=f2bf(a1.x); v[5]=f2bf(a1.y); v[6]=f2bf(a1.z); v[7]=f2bf(a1.w);
    } else if (i8 >= XP_REAL) {
        #pragma unroll
        for (int j = 0; j < 8; ++j) v[j] = 0;        // zero slack (frames > 3750)
    } else {
        #pragma unroll
        for (int j = 0; j < 8; ++j) {
            int idx = ix + j;
            idx = idx < 0 ? -idx : idx;
            idx = idx >= NS ? 2 * NS - 2 - idx : idx;
            v[j] = f2bf(xb[idx]);
        }
    }
    *reinterpret_cast<short8*>(xp + (size_t)b * XPS + i8) = v;
}

// ---- prep 2: bf16 basis, rows padded to 320 ----
__global__ __launch_bounds__(256)
void prep_basis(const float* __restrict__ basis, short* __restrict__ ab) {
    int g = blockIdx.x * 256 + threadIdx.x;          // 2*320*512/8 = 40960 groups
    if (g >= 40960) return;
    int ri  = g / 20480;
    int rem = g - ri * 20480;
    int r   = rem >> 6;
    int k   = (rem & 63) * 8;
    short8 v;
    if (r < NFREQ) {
        const float4* p = reinterpret_cast<const float4*>(basis + ((size_t)(ri * NFREQ + r)) * WIN + k);
        float4 a0 = p[0], a1 = p[1];
        v[0]=f2bf(a0.x); v[1]=f2bf(a0.y); v[2]=f2bf(a0.z); v[3]=f2bf(a0.w);
        v[4]=f2bf(a1.x); v[5]=f2bf(a1.y); v[6]=f2bf(a1.z); v[7]=f2bf(a1.w);
    } else {
        #pragma unroll
        for (int j = 0; j < 8; ++j) v[j] = 0;
    }
    *reinterpret_cast<short8*>(ab + ((size_t)ri * AROWS + r) * WIN + k) = v;
}

// ---- main: x-window staged once; 2-phase double-buffered A pipeline ----
__global__ __launch_bounds__(256, 2)
void stft_mfma_kernel(const short* __restrict__ xp,
                      const short* __restrict__ ab,
                      float* __restrict__ out)
{
    __shared__ __align__(16) char smem[XW_B + 2 * AHALF];   // 66560 B -> 2 blocks/CU
    char* const xw   = smem;
    char* const aBuf = smem + XW_B;

    const int tid  = threadIdx.x;
    const int wave = tid >> 6;
    const int lane = tid & 63;
    const int wr   = wave >> 1;          // wave freq row (0..1)
    const int wc   = wave & 1;           // wave frame col (0..1)
    const int lgrp = lane >> 4;
    const int l15  = lane & 15;

    // bijective XCD chunk swizzle: 960 = 8 * 120
    const int logical = (blockIdx.x & 7) * 120 + (blockIdx.x >> 3);
    const int ft = logical % NFT;
    const int b  = logical / NFT;
    const int t0 = ft * BN;

    const char* abG = (const char*)ab;
    const int cbs = 16 * ((lane & 7) ^ (lane >> 3));   // per-lane A source swizzle

    // ---- prologue: stage x window (once) + A tile for s=0; drain; barrier ----
    const char* xwg = (const char*)(xp + (size_t)b * XPS) + (size_t)t0 * 256;
    #pragma unroll
    for (int i = 0; i < 9; ++i) {
        int c = i * 4 + wave;
        if (c < 33) {
            int off = c * 1024 + lane * 16;
            int src = off ^ (((off >> 8) & 7) << 4);
            gload_lds16(xwg + src, xw + c * 1024);
        }
    }
    #pragma unroll
    for (int i = 0; i < 4; ++i) {
        int c = wave * 4 + i;                        // 0..15
        int r = (c & 7) * 8 + (lane >> 3);           // row 0..63
        const char* src = abG + (c < 8 ? 0 : AIMAG_B) + (size_t)r * 1024 + cbs;
        gload_lds16(src, aBuf + (c < 8 ? 0 : 8192) + (c & 7) * 1024);
    }
    asm volatile("s_waitcnt vmcnt(0)" ::: "memory");
    __builtin_amdgcn_sched_barrier(0);
    __syncthreads();
    __builtin_amdgcn_sched_barrier(0);

    f32x4 accR[2][4], accI[2][4];
    #pragma unroll
    for (int m = 0; m < 2; ++m)
        #pragma unroll
        for (int nt = 0; nt < 4; ++nt) {
            accR[m][nt] = f32x4{0.f, 0.f, 0.f, 0.f};
            accI[m][nt] = f32x4{0.f, 0.f, 0.f, 0.f};
        }

    #pragma unroll 1
    for (int s = 0; s < STEPS; ++s) {
        char* const aCur = aBuf + (s & 1) * AHALF;

        // ---- stage NEXT A tile into the other buffer ----
        if (s + 1 < STEPS) {
            char* const aNxt = aBuf + ((s + 1) & 1) * AHALF;
            const int fq  = (s + 1) >> 3;
            const int ksb = ((s + 1) & 7) * 128;
            #pragma unroll
            for (int i = 0; i < 4; ++i) {
                int c = wave * 4 + i;
                int r = (c & 7) * 8 + (lane >> 3);
                const char* src = abG + (c < 8 ? 0 : AIMAG_B)
                                + (size_t)(fq * 64 + r) * 1024 + ksb + cbs;
                gload_lds16(src, aNxt + (c < 8 ? 0 : 8192) + (c & 7) * 1024);
            }
        }
        __builtin_amdgcn_sched_barrier(0);   // pin: stages issued before compute

        // ---- compute current step from aCur ----
        const int ksb2 = (s & 7) * 128;
        #pragma unroll
        for (int ko = 0; ko < 2; ++ko) {
            const int kb = ko * 64 + lgrp * 16;
            short8 aRv[2], aIv[2], xv[4];
            #pragma unroll
            for (int m = 0; m < 2; ++m) {
                int row = wr * 32 + m * 16 + l15;
                int o = row * 128 + (kb ^ ((row & 7) << 4));
                aRv[m] = *reinterpret_cast<const short8*>(aCur + o);
                aIv[m] = *reinterpret_cast<const short8*>(aCur + 8192 + o);
            }
            #pragma unroll
            for (int nt = 0; nt < 4; ++nt) {
                int tl = wc * 64 + nt * 16 + l15;
                int flat = tl * 256 + ksb2 + ko * 64 + lgrp * 16;
                xv[nt] = *reinterpret_cast<const short8*>(xw + (flat ^ (((flat >> 8) & 7) << 4)));
            }
            #pragma unroll
            for (int m = 0; m < 2; ++m)
                #pragma unroll
                for (int nt = 0; nt < 4; ++nt) {
                    accR[m][nt] = __builtin_amdgcn_mfma_f32_16x16x32_bf16(aRv[m], xv[nt], accR[m][nt], 0, 0, 0);
                    accI[m][nt] = __builtin_amdgcn_mfma_f32_16x16x32_bf16(aIv[m], xv[nt], accI[m][nt], 0, 0, 0);
                }
        }

        // ---- per-freq-tile epilogue (after ks=7 of each fq) ----
        if ((s & 7) == 7) {
            const int fq = s >> 3;
            const int fBase = fq * 64 + wr * 32 + lgrp * 4;
            const int tBase = t0 + wc * 64 + l15;
            float* ob = out + (size_t)b * NFREQ * NFRAMES;
            #pragma unroll
            for (int m = 0; m < 2; ++m)
                #pragma unroll
                for (int nt = 0; nt < 4; ++nt) {
                    int t = tBase + nt * 16;
                    if (t < NFRAMES) {
                        #pragma unroll
                        for (int r = 0; r < 4; ++r) {
                            int f = fBase + m * 16 + r;
                            if (f < NFREQ) {
                                float vr = accR[m][nt][r], vi = accI[m][nt][r];
                                ob[(size_t)f * NFRAMES + t] = sqrtf(vr * vr + vi * vi);
                            }
                        }
                    }
                    accR[m][nt] = f32x4{0.f, 0.f, 0.f, 0.f};
                    accI[m][nt] = f32x4{0.f, 0.f, 0.f, 0.f};
                }
        }

        // ---- drain this iteration's stage; one barrier per step ----
        asm volatile("s_waitcnt vmcnt(0)" ::: "memory");
        __builtin_amdgcn_sched_barrier(0);
        __syncthreads();
        __builtin_amdgcn_sched_barrier(0);
    }
}

extern "C" void kernel_launch(void* const* d_in, const int* in_sizes, int n_in,
                              void* d_out, int out_size, void* d_ws, size_t ws_size,
                              hipStream_t stream) {
    const float* x     = (const float*)d_in[0];
    const float* basis = (const float*)d_in[1];
    float* out = (float*)d_out;

    short* xp = (short*)d_ws;                         // 32*491904 bf16
    short* ab = xp + (size_t)NB * XPS;                // 2*320*512 bf16

    prep_x<<<dim3((NB * (XPS / 8) + 255) / 256), 256, 0, stream>>>(x, xp);
    prep_basis<<<dim3(160), 256, 0, stream>>>(basis, ab);

    stft_mfma_kernel<<<dim3(NFT * NB), 256, 0, stream>>>(xp, ab, out);  // 960 blocks
}